// Round 9
// baseline (194.964 us; speedup 1.0000x reference)
//
#include <hip/hip_runtime.h>

typedef _Float16 f16;
typedef __attribute__((ext_vector_type(2))) _Float16 f16x2;
typedef __attribute__((ext_vector_type(4))) _Float16 f16x4;
typedef __attribute__((ext_vector_type(8))) _Float16 f16x8;
typedef __attribute__((ext_vector_type(4))) float    f32x4;
typedef __attribute__((ext_vector_type(16))) float   f32x16;
typedef __attribute__((ext_vector_type(4))) unsigned u32x4;

static constexpr int B_ = 2, N_ = 2048, E_ = 1024, H_ = 16, D_ = 64;
static constexpr int M_ = B_ * N_;   // 4096

#define MFMA16(a, b, c) __builtin_amdgcn_mfma_f32_16x16x32_f16(a, b, c, 0, 0, 0)
#define MFMA32(a, b, c) __builtin_amdgcn_mfma_f32_32x32x16_f16(a, b, c, 0, 0, 0)

// q-projection scale: 1/sqrt(D) * log2(e)  (softmax done in exp2 domain)
#define QSCALE 0.18033688011112042f

// async global(16B/lane) -> LDS (wave-uniform base + lane*16)
__device__ __forceinline__ void gload_lds16(const f16* g, f16* l) {
    typedef __attribute__((address_space(1))) const unsigned gu32;
    typedef __attribute__((address_space(3))) unsigned       lu32;
    __builtin_amdgcn_global_load_lds((gu32*)g, (lu32*)l, 16, 0, 0);
}

// ---------------------------------------------------------------------------
// Kernel 1: cast weights (4*E*E) AND q/k/v (3*M*E) fp32 -> f16 into one flat
// region: [Wq|Wk|Wv|Wo | q|k|v].
// ---------------------------------------------------------------------------
__global__ __launch_bounds__(256) void cast_all(
    const float* __restrict__ Wq, const float* __restrict__ Wk,
    const float* __restrict__ Wv, const float* __restrict__ Wo,
    const float* __restrict__ q, const float* __restrict__ k,
    const float* __restrict__ v, f16* __restrict__ dst)
{
    const int i = (blockIdx.x * 256 + threadIdx.x) * 4;
    const float* s;
    int j;
    if (i < 4 * E_ * E_) {
        const int which = i >> 20;                        // E*E = 2^20
        s = (which == 0) ? Wq : (which == 1) ? Wk : (which == 2) ? Wv : Wo;
        j = i & (E_ * E_ - 1);
    } else {
        const int t = i - 4 * E_ * E_;
        const int which = t >> 22;                        // M*E = 2^22
        s = (which == 0) ? q : (which == 1) ? k : v;
        j = t & (M_ * E_ - 1);
    }
    const f32x4 f = *(const f32x4*)&s[j];
    f16x4 o;
    o[0] = (f16)f[0]; o[1] = (f16)f[1]; o[2] = (f16)f[2]; o[3] = (f16)f[3];
    *(f16x4*)&dst[i] = o;
}

// ---------------------------------------------------------------------------
// Kernel 2: projection GEMM, m97-structure (global_load_lds, linear LDS,
//   XOR-chunk swizzle via pre-swizzled global source).
//   Epilogue: q -> qh (linear, scaled by QSCALE); k -> kh with d-chunk XOR
//   pre-swizzle; v -> vt[b,h,d,n] with kv-chunk XOR pre-swizzle.
// ---------------------------------------------------------------------------
__global__ __launch_bounds__(256) void proj_gemm(
    const f16* __restrict__ Aall, const f16* __restrict__ Wb,
    const float* __restrict__ bq, const float* __restrict__ bk, const float* __restrict__ bv,
    f16* __restrict__ qh, f16* __restrict__ kh, f16* __restrict__ vt)
{
    const int bid  = blockIdx.x;
    const int lin  = (bid & 7) * 96 + (bid >> 3);
    const int z    = lin >> 8;
    const int rem  = lin & 255;
    const int m0   = (rem >> 3) * 128;
    const int n0   = (rem & 7) * 128;

    const f16* A    = Aall + (size_t)z * M_ * E_;
    const f16* W    = Wb + (size_t)z * E_ * E_;
    const float* bias = (z == 0) ? bq : (z == 1) ? bk : bv;

    __shared__ f16 As[128][32];
    __shared__ f16 Bs[128][32];

    const int tid  = threadIdx.x;
    const int lane = tid & 63, w = tid >> 6;
    const int lr = lane & 15, lg = lane >> 4;
    const int wm = (w >> 1) * 64, wn = (w & 1) * 64;

    const int gch = ((lane & 3) ^ ((lane >> 3) & 3)) * 8;
    const f16* ag = A + (size_t)(m0 + w * 32 + (lane >> 2)) * E_ + gch;
    const f16* bg = W + (size_t)(n0 + w * 32 + (lane >> 2)) * E_ + gch;
    f16* al0 = &As[w * 32][0];
    f16* al1 = &As[w * 32 + 16][0];
    f16* bl0 = &Bs[w * 32][0];
    f16* bl1 = &Bs[w * 32 + 16][0];

    const int ca = (lg ^ ((lr >> 1) & 3)) * 8;

    f32x4 acc[4][4];
#pragma unroll
    for (int i = 0; i < 4; i++)
#pragma unroll
        for (int j = 0; j < 4; j++) acc[i][j] = (f32x4){0.f, 0.f, 0.f, 0.f};

    for (int t = 0; t < E_ / 32; ++t) {
        __syncthreads();
        gload_lds16(ag,            al0);
        gload_lds16(ag + 16 * E_,  al1);
        gload_lds16(bg,            bl0);
        gload_lds16(bg + 16 * E_,  bl1);
        ag += 32; bg += 32;
        __syncthreads();

        f16x8 af[4], bfr[4];
#pragma unroll
        for (int ms = 0; ms < 4; ms++) af[ms]  = *(const f16x8*)&As[wm + ms * 16 + lr][ca];
#pragma unroll
        for (int ns = 0; ns < 4; ns++) bfr[ns] = *(const f16x8*)&Bs[wn + ns * 16 + lr][ca];
        __builtin_amdgcn_s_setprio(1);
#pragma unroll
        for (int ms = 0; ms < 4; ms++)
#pragma unroll
            for (int ns = 0; ns < 4; ns++)
                acc[ms][ns] = MFMA16(af[ms], bfr[ns], acc[ms][ns]);
        __builtin_amdgcn_s_setprio(0);
    }

    const float oscale = (z == 0) ? QSCALE : 1.0f;
#pragma unroll
    for (int ms = 0; ms < 4; ms++) {
        const int mbase = m0 + wm + ms * 16 + lg * 4;
#pragma unroll
        for (int ns = 0; ns < 4; ns++) {
            const int n  = n0 + wn + ns * 16 + lr;
            const float bn = bias[n];
            const int hh = n >> 6, dd = n & 63;
#pragma unroll
            for (int r = 0; r < 4; r++) {
                const float val = (acc[ms][ns][r] + bn) * oscale;
                const int mm = mbase + r;
                const int bb = mm >> 11;
                const int nn = mm & (N_ - 1);
                if (z == 0) {
                    qh[((size_t)(bb * H_ + hh) * N_ + nn) * D_ + dd] = (f16)val;
                } else if (z == 1) {
                    const int ddsw = ((((dd >> 3) ^ nn) & 7) << 3) | (dd & 7);
                    kh[((size_t)(bb * H_ + hh) * N_ + nn) * D_ + ddsw] = (f16)val;
                } else {
                    const int nnsw = (nn & ~63) | ((((nn >> 3) ^ dd) & 7) << 3) | (nn & 7);
                    vt[((size_t)(bb * H_ + hh) * D_ + dd) * N_ + nnsw] = (f16)val;
                }
            }
        }
    }
}

// ---------------------------------------------------------------------------
// Kernel 3: flash attention. 1024 blocks (32 q-tiles x 32 bh, XCD-swz),
//  4 waves = 2 q-groups x 2 kv-halves; block-local merge at the end.
//  T14 reg-staged K/V: ds_write tile t, issue K loads t+1 (hidden under
//  QK+softmax), issue V loads t+1 after QK (hidden under PV). Single-buffer
//  LDS 32KB -> 4 blocks/CU.
// ---------------------------------------------------------------------------
__global__ __launch_bounds__(256, 4) void attn_kernel(
    const f16* __restrict__ qh, const f16* __restrict__ kh,
    const f16* __restrict__ vt, f16* __restrict__ ao)
{
    const int bid = blockIdx.x;
    const int swz = (bid & 7) * 128 + (bid >> 3);   // 1024 blocks, 8 XCDs
    const int qt = swz & 31;            // 32 q-tiles of 64 rows
    const int bh = swz >> 5;            // 0..31

    const int tid = threadIdx.x;
    const int w = tid >> 6, lane = tid & 63;
    const int qg = w & 1, kvg = w >> 1;
    const int l31 = lane & 31;
    const bool hi = (lane >> 5) != 0;
    const int hib = hi ? 1 : 0;

    const f16* qp = qh + (size_t)bh * N_ * D_;
    const f16* kp = kh + (size_t)bh * N_ * D_;
    const f16* vp = vt + (size_t)bh * D_ * N_;

    const int qrow = qt * 64 + qg * 32 + l31;

    f16x8 qf[4];
#pragma unroll
    for (int ks = 0; ks < 4; ks++)
        qf[ks] = *(const f16x8*)&qp[(size_t)qrow * D_ + ks * 16 + hib * 8];

    __shared__ union SmemU {
        struct { f16 K[2][64][64]; f16 V[2][64][64]; } s;   // [kvg][row][64]
        float M[2][64][34];                                  // merge buffer
    } sm;

    // staging coords: wave covers rows qg*32 + i*8 + (lane>>3), chunk lane&7
    const int srow = lane >> 3;
    const int sch8 = (lane & 7) * 8;
    const f16* kgb = kp + ((size_t)(kvg * 1024 + qg * 32 + srow)) * 64 + sch8;
    const f16* vgb = vp + (size_t)(qg * 32 + srow) * N_ + kvg * 1024 + sch8;

    f32x16 oT0 = {0.f,0.f,0.f,0.f,0.f,0.f,0.f,0.f,0.f,0.f,0.f,0.f,0.f,0.f,0.f,0.f};
    f32x16 oT1 = oT0;
    float mrun = -3.0e38f, lrun = 0.f;

    // prologue: tile 0 into regs
    f16x8 kreg[4], vreg[4];
#pragma unroll
    for (int i = 0; i < 4; i++) {
        kreg[i] = *(const f16x8*)(kgb + (size_t)i * 512);          // 8 rows = 512 f16
        vreg[i] = *(const f16x8*)(vgb + (size_t)i * 8 * N_);
    }

    for (int t = 0; t < 16; ++t) {
        __syncthreads();                 // all waves done reading prev tile
#pragma unroll
        for (int i = 0; i < 4; i++) {
            *(f16x8*)&sm.s.K[kvg][qg * 32 + i * 8 + srow][sch8] = kreg[i];
            *(f16x8*)&sm.s.V[kvg][qg * 32 + i * 8 + srow][sch8] = vreg[i];
        }
        // issue next-tile K loads now (latency hides under QK+softmax+PV)
        if (t + 1 < 16) {
#pragma unroll
            for (int i = 0; i < 4; i++)
                kreg[i] = *(const f16x8*)(kgb + (size_t)(t + 1) * 4096 + i * 512);
        }
        __syncthreads();                 // staged writes visible

        // ---- S^T = K . Q^T ----
        f32x16 sA = {0.f,0.f,0.f,0.f,0.f,0.f,0.f,0.f,0.f,0.f,0.f,0.f,0.f,0.f,0.f,0.f};
        f32x16 sB = sA;
        __builtin_amdgcn_s_setprio(1);
#pragma unroll
        for (int ks = 0; ks < 4; ks++) {
            const int c = (ks * 2 + hib) ^ (l31 & 7);
            const f16x8 kfA = *(const f16x8*)&sm.s.K[kvg][l31     ][c * 8];
            const f16x8 kfB = *(const f16x8*)&sm.s.K[kvg][l31 + 32][c * 8];
            sA = MFMA32(kfA, qf[ks], sA);
            sB = MFMA32(kfB, qf[ks], sB);
        }
        __builtin_amdgcn_s_setprio(0);

        // issue next-tile V loads (latency hides under softmax+PV)
        if (t + 1 < 16) {
#pragma unroll
            for (int i = 0; i < 4; i++)
                vreg[i] = *(const f16x8*)(vgb + (t + 1) * 64 + (size_t)i * 8 * N_);
        }

        // ---- tile max (max3-shaped tree) ----
        float t16[16];
#pragma unroll
        for (int r = 0; r < 16; r++) t16[r] = fmaxf(sA[r], sB[r]);
        const float u0 = fmaxf(fmaxf(t16[0],  t16[1]),  t16[2]);
        const float u1 = fmaxf(fmaxf(t16[3],  t16[4]),  t16[5]);
        const float u2 = fmaxf(fmaxf(t16[6],  t16[7]),  t16[8]);
        const float u3 = fmaxf(fmaxf(t16[9],  t16[10]), t16[11]);
        const float u4 = fmaxf(fmaxf(t16[12], t16[13]), t16[14]);
        const float v0 = fmaxf(fmaxf(u0, u1), u2);
        const float v1 = fmaxf(fmaxf(u3, u4), t16[15]);
        const float tmax = fmaxf(v0, v1);
        const float pmax = fmaxf(tmax, __shfl_xor(tmax, 32));

        if (!__all(pmax - mrun <= 8.0f)) {
            const float mnew = fmaxf(mrun, pmax);
            const float alpha = __builtin_amdgcn_exp2f(mrun - mnew);
            mrun = mnew;
            lrun *= alpha;
#pragma unroll
            for (int r = 0; r < 16; r++) { oT0[r] *= alpha; oT1[r] *= alpha; }
        }

        float p0 = 0.f, p1 = 0.f, p2 = 0.f, p3 = 0.f;
#pragma unroll
        for (int r = 0; r < 16; r += 4) {
            sA[r]   = __builtin_amdgcn_exp2f(sA[r]   - mrun); p0 += sA[r];
            sA[r+1] = __builtin_amdgcn_exp2f(sA[r+1] - mrun); p1 += sA[r+1];
            sA[r+2] = __builtin_amdgcn_exp2f(sA[r+2] - mrun); p2 += sA[r+2];
            sA[r+3] = __builtin_amdgcn_exp2f(sA[r+3] - mrun); p3 += sA[r+3];
        }
#pragma unroll
        for (int r = 0; r < 16; r += 4) {
            sB[r]   = __builtin_amdgcn_exp2f(sB[r]   - mrun); p0 += sB[r];
            sB[r+1] = __builtin_amdgcn_exp2f(sB[r+1] - mrun); p1 += sB[r+1];
            sB[r+2] = __builtin_amdgcn_exp2f(sB[r+2] - mrun); p2 += sB[r+2];
            sB[r+3] = __builtin_amdgcn_exp2f(sB[r+3] - mrun); p3 += sB[r+3];
        }
        float lsum = (p0 + p1) + (p2 + p3);
        lsum += __shfl_xor(lsum, 32);
        lrun += lsum;

        // ---- P -> B-frag via cvt_pkrtz + shfl_xor(32) + select (PROVEN) ----
        __builtin_amdgcn_s_setprio(1);
#define PVSTEP(PP0,PP1,PP2,PP3,PP4,PP5,PP6,PP7, KSI)                                   \
        {                                                                              \
            const unsigned w0 = __builtin_bit_cast(unsigned, __builtin_amdgcn_cvt_pkrtz(PP0, PP1)); \
            const unsigned w1 = __builtin_bit_cast(unsigned, __builtin_amdgcn_cvt_pkrtz(PP2, PP3)); \
            const unsigned w2 = __builtin_bit_cast(unsigned, __builtin_amdgcn_cvt_pkrtz(PP4, PP5)); \
            const unsigned w3 = __builtin_bit_cast(unsigned, __builtin_amdgcn_cvt_pkrtz(PP6, PP7)); \
            const unsigned x0 = (unsigned)__shfl_xor((int)w0, 32);                     \
            const unsigned x1 = (unsigned)__shfl_xor((int)w1, 32);                     \
            const unsigned x2 = (unsigned)__shfl_xor((int)w2, 32);                     \
            const unsigned x3 = (unsigned)__shfl_xor((int)w3, 32);                     \
            u32x4 pw;                                                                  \
            pw[0] = hi ? x2 : w0;                                                      \
            pw[1] = hi ? x3 : w1;                                                      \
            pw[2] = hi ? w2 : x0;                                                      \
            pw[3] = hi ? w3 : x1;                                                      \
            const f16x8 pa = __builtin_bit_cast(f16x8, pw);                            \
            const int c = ((KSI) * 2 + hib) ^ (l31 & 7);                               \
            const f16x8 vf0 = *(const f16x8*)&sm.s.V[kvg][l31     ][c * 8];            \
            const f16x8 vf1 = *(const f16x8*)&sm.s.V[kvg][l31 + 32][c * 8];            \
            oT0 = MFMA32(vf0, pa, oT0);                                                \
            oT1 = MFMA32(vf1, pa, oT1);                                                \
        }
        PVSTEP(sA[0],sA[1],sA[2],sA[3],sA[4],sA[5],sA[6],sA[7], 0)
        PVSTEP(sA[8],sA[9],sA[10],sA[11],sA[12],sA[13],sA[14],sA[15], 1)
        PVSTEP(sB[0],sB[1],sB[2],sB[3],sB[4],sB[5],sB[6],sB[7], 2)
        PVSTEP(sB[8],sB[9],sB[10],sB[11],sB[12],sB[13],sB[14],sB[15], 3)
#undef PVSTEP
        __builtin_amdgcn_s_setprio(0);
    }

    // ---- block-local kv-merge + epilogue ----
    __syncthreads();                     // all K/V LDS reads done; union free
    if (kvg == 1) {
        float* Mq = &sm.M[qg][lane][0];
#pragma unroll
        for (int r = 0; r < 16; r++) { Mq[r] = oT0[r]; Mq[16 + r] = oT1[r]; }
        Mq[32] = mrun; Mq[33] = lrun;
    }
    __syncthreads();
    if (kvg == 0) {
        const float* Mq = &sm.M[qg][lane][0];
        const float pm = Mq[32], pl = Mq[33];
        const float m  = fmaxf(mrun, pm);
        const float a1 = __builtin_amdgcn_exp2f(mrun - m);
        const float a2 = __builtin_amdgcn_exp2f(pm - m);
        const float inv = 1.0f / (lrun * a1 + pl * a2);
        const int b = bh >> 4, h = bh & 15;
        f16* dst = ao + (size_t)(b * N_ + qrow) * E_ + h * 64 + hib * 4;
#pragma unroll
        for (int g = 0; g < 4; g++) {
            f16x4 o0, o1;
#pragma unroll
            for (int j = 0; j < 4; j++) {
                o0[j] = (f16)((oT0[g * 4 + j] * a1 + Mq[g * 4 + j]      * a2) * inv);
                o1[j] = (f16)((oT1[g * 4 + j] * a1 + Mq[16 + g * 4 + j] * a2) * inv);
            }
            *(f16x4*)&dst[8 * g]      = o0;
            *(f16x4*)&dst[8 * g + 32] = o1;
        }
    }
}

// ---------------------------------------------------------------------------
// Kernel 4: output GEMM, m97-structure.  out[m,n] = ao[m,:].Wo[n,:] + bo[n]
// ---------------------------------------------------------------------------
__global__ __launch_bounds__(256) void out_gemm(
    const f16* __restrict__ ao, const f16* __restrict__ Wo,
    const float* __restrict__ bo, float* __restrict__ out)
{
    __shared__ f16 As[128][32];
    __shared__ f16 Bs[128][32];

    const int bid = blockIdx.x;
    const int lin = (bid & 7) * 32 + (bid >> 3);
    const int m0  = (lin >> 3) * 128;
    const int n0  = (lin & 7) * 128;

    const int tid  = threadIdx.x;
    const int lane = tid & 63, w = tid >> 6;
    const int lr = lane & 15, lg = lane >> 4;
    const int wm = (w >> 1) * 64, wn = (w & 1) * 64;

    const int gch = ((lane & 3) ^ ((lane >> 3) & 3)) * 8;
    const f16* ag = ao + (size_t)(m0 + w * 32 + (lane >> 2)) * E_ + gch;
    const f16* bg = Wo + (size_t)(n0 + w * 32 + (lane >> 2)) * E_ + gch;
    f16* al0 = &As[w * 32][0];
    f16* al1 = &As[w * 32 + 16][0];
    f16* bl0 = &Bs[w * 32][0];
    f16* bl1 = &Bs[w * 32 + 16][0];

    const int ca = (lg ^ ((lr >> 1) & 3)) * 8;

    f32x4 acc[4][4];
#pragma unroll
    for (int i = 0; i < 4; i++)
#pragma unroll
        for (int j = 0; j < 4; j++) acc[i][j] = (f32x4){0.f, 0.f, 0.f, 0.f};

    for (int t = 0; t < E_ / 32; ++t) {
        __syncthreads();
        gload_lds16(ag,            al0);
        gload_lds16(ag + 16 * E_,  al1);
        gload_lds16(bg,            bl0);
        gload_lds16(bg + 16 * E_,  bl1);
        ag += 32; bg += 32;
        __syncthreads();

        f16x8 af[4], bfr[4];
#pragma unroll
        for (int ms = 0; ms < 4; ms++) af[ms]  = *(const f16x8*)&As[wm + ms * 16 + lr][ca];
#pragma unroll
        for (int ns = 0; ns < 4; ns++) bfr[ns] = *(const f16x8*)&Bs[wn + ns * 16 + lr][ca];
        __builtin_amdgcn_s_setprio(1);
#pragma unroll
        for (int ms = 0; ms < 4; ms++)
#pragma unroll
            for (int ns = 0; ns < 4; ns++)
                acc[ms][ns] = MFMA16(af[ms], bfr[ns], acc[ms][ns]);
        __builtin_amdgcn_s_setprio(0);
    }

#pragma unroll
    for (int ms = 0; ms < 4; ms++) {
        const int mbase = m0 + wm + ms * 16 + lg * 4;
#pragma unroll
        for (int ns = 0; ns < 4; ns++) {
            const int n = n0 + wn + ns * 16 + lr;
            const float bn = bo[n];
#pragma unroll
            for (int r = 0; r < 4; r++) {
                out[(size_t)(mbase + r) * E_ + n] = acc[ms][ns][r] + bn;
            }
        }
    }
}

// ---------------------------------------------------------------------------
extern "C" void kernel_launch(void* const* d_in, const int* in_sizes, int n_in,
                              void* d_out, int out_size, void* d_ws, size_t ws_size,
                              hipStream_t stream) {
    const float* q  = (const float*)d_in[0];
    const float* k  = (const float*)d_in[1];
    const float* v  = (const float*)d_in[2];
    const float* Wq = (const float*)d_in[3];
    const float* bq = (const float*)d_in[4];
    const float* Wk = (const float*)d_in[5];
    const float* bk = (const float*)d_in[6];
    const float* Wv = (const float*)d_in[7];
    const float* bv = (const float*)d_in[8];
    const float* Wo = (const float*)d_in[9];
    const float* bo = (const float*)d_in[10];
    float* out = (float*)d_out;

    char* ws = (char*)d_ws;
    f16* cast = (f16*)ws;
    f16* Wb   = cast;
    f16* Aall = cast + (size_t)4 * E_ * E_;
    f16* qh = (f16*)(ws + (size_t)32 * 1024 * 1024);
    f16* kh = (f16*)(ws + (size_t)40 * 1024 * 1024);
    f16* vt = (f16*)(ws + (size_t)48 * 1024 * 1024);
    f16* ao = (f16*)(ws + (size_t)56 * 1024 * 1024);

    cast_all<<<16384, 256, 0, stream>>>(Wq, Wk, Wv, Wo, q, k, v, cast);
    proj_gemm<<<768, 256, 0, stream>>>(Aall, Wb, bq, bk, bv, qh, kh, vt);
    attn_kernel<<<1024, 256, 0, stream>>>(qh, kh, vt, ao);
    out_gemm<<<256, 256, 0, stream>>>(ao, Wb + (size_t)3 * E_ * E_, bo, out);
}

// Round 10
// 156.298 us; speedup vs baseline: 1.2474x; 1.2474x over previous
//
#include <hip/hip_runtime.h>

typedef _Float16 f16;
typedef __attribute__((ext_vector_type(2))) _Float16 f16x2;
typedef __attribute__((ext_vector_type(4))) _Float16 f16x4;
typedef __attribute__((ext_vector_type(8))) _Float16 f16x8;
typedef __attribute__((ext_vector_type(4))) float    f32x4;
typedef __attribute__((ext_vector_type(16))) float   f32x16;
typedef __attribute__((ext_vector_type(4))) unsigned u32x4;

static constexpr int B_ = 2, N_ = 2048, E_ = 1024, H_ = 16, D_ = 64;
static constexpr int M_ = B_ * N_;   // 4096

#define MFMA16(a, b, c) __builtin_amdgcn_mfma_f32_16x16x32_f16(a, b, c, 0, 0, 0)
#define MFMA32(a, b, c) __builtin_amdgcn_mfma_f32_32x32x16_f16(a, b, c, 0, 0, 0)

// q-projection scale: 1/sqrt(D) * log2(e)  (softmax done in exp2 domain)
#define QSCALE 0.18033688011112042f

// async global(16B/lane) -> LDS (wave-uniform base + lane*16)
__device__ __forceinline__ void gload_lds16(const f16* g, f16* l) {
    typedef __attribute__((address_space(1))) const unsigned gu32;
    typedef __attribute__((address_space(3))) unsigned       lu32;
    __builtin_amdgcn_global_load_lds((gu32*)g, (lu32*)l, 16, 0, 0);
}

// ---------------------------------------------------------------------------
// Kernel 1: cast weights (4*E*E) AND q/k/v (3*M*E) fp32 -> f16 into one flat
// region: [Wq|Wk|Wv|Wo | q|k|v].
// ---------------------------------------------------------------------------
__global__ __launch_bounds__(256) void cast_all(
    const float* __restrict__ Wq, const float* __restrict__ Wk,
    const float* __restrict__ Wv, const float* __restrict__ Wo,
    const float* __restrict__ q, const float* __restrict__ k,
    const float* __restrict__ v, f16* __restrict__ dst)
{
    const int i = (blockIdx.x * 256 + threadIdx.x) * 4;
    const float* s;
    int j;
    if (i < 4 * E_ * E_) {
        const int which = i >> 20;                        // E*E = 2^20
        s = (which == 0) ? Wq : (which == 1) ? Wk : (which == 2) ? Wv : Wo;
        j = i & (E_ * E_ - 1);
    } else {
        const int t = i - 4 * E_ * E_;
        const int which = t >> 22;                        // M*E = 2^22
        s = (which == 0) ? q : (which == 1) ? k : v;
        j = t & (M_ * E_ - 1);
    }
    const f32x4 f = *(const f32x4*)&s[j];
    f16x4 o;
    o[0] = (f16)f[0]; o[1] = (f16)f[1]; o[2] = (f16)f[2]; o[3] = (f16)f[3];
    *(f16x4*)&dst[i] = o;
}

// ---------------------------------------------------------------------------
// Kernel 2: projection GEMM, m97-structure (global_load_lds, linear LDS,
//   XOR-chunk swizzle via pre-swizzled global source).  R6-proven version:
//   Epilogue: q -> qh (scaled by QSCALE), k -> kh, v -> vt[b,h,d,n], all linear.
// ---------------------------------------------------------------------------
__global__ __launch_bounds__(256) void proj_gemm(
    const f16* __restrict__ Aall, const f16* __restrict__ Wb,
    const float* __restrict__ bq, const float* __restrict__ bk, const float* __restrict__ bv,
    f16* __restrict__ qh, f16* __restrict__ kh, f16* __restrict__ vt)
{
    const int bid  = blockIdx.x;
    const int lin  = (bid & 7) * 96 + (bid >> 3);
    const int z    = lin >> 8;
    const int rem  = lin & 255;
    const int m0   = (rem >> 3) * 128;
    const int n0   = (rem & 7) * 128;

    const f16* A    = Aall + (size_t)z * M_ * E_;
    const f16* W    = Wb + (size_t)z * E_ * E_;
    const float* bias = (z == 0) ? bq : (z == 1) ? bk : bv;

    __shared__ f16 As[128][32];
    __shared__ f16 Bs[128][32];

    const int tid  = threadIdx.x;
    const int lane = tid & 63, w = tid >> 6;
    const int lr = lane & 15, lg = lane >> 4;
    const int wm = (w >> 1) * 64, wn = (w & 1) * 64;

    const int gch = ((lane & 3) ^ ((lane >> 3) & 3)) * 8;
    const f16* ag = A + (size_t)(m0 + w * 32 + (lane >> 2)) * E_ + gch;
    const f16* bg = W + (size_t)(n0 + w * 32 + (lane >> 2)) * E_ + gch;
    f16* al0 = &As[w * 32][0];
    f16* al1 = &As[w * 32 + 16][0];
    f16* bl0 = &Bs[w * 32][0];
    f16* bl1 = &Bs[w * 32 + 16][0];

    const int ca = (lg ^ ((lr >> 1) & 3)) * 8;

    f32x4 acc[4][4];
#pragma unroll
    for (int i = 0; i < 4; i++)
#pragma unroll
        for (int j = 0; j < 4; j++) acc[i][j] = (f32x4){0.f, 0.f, 0.f, 0.f};

    for (int t = 0; t < E_ / 32; ++t) {
        __syncthreads();
        gload_lds16(ag,            al0);
        gload_lds16(ag + 16 * E_,  al1);
        gload_lds16(bg,            bl0);
        gload_lds16(bg + 16 * E_,  bl1);
        ag += 32; bg += 32;
        __syncthreads();

        f16x8 af[4], bfr[4];
#pragma unroll
        for (int ms = 0; ms < 4; ms++) af[ms]  = *(const f16x8*)&As[wm + ms * 16 + lr][ca];
#pragma unroll
        for (int ns = 0; ns < 4; ns++) bfr[ns] = *(const f16x8*)&Bs[wn + ns * 16 + lr][ca];
        __builtin_amdgcn_s_setprio(1);
#pragma unroll
        for (int ms = 0; ms < 4; ms++)
#pragma unroll
            for (int ns = 0; ns < 4; ns++)
                acc[ms][ns] = MFMA16(af[ms], bfr[ns], acc[ms][ns]);
        __builtin_amdgcn_s_setprio(0);
    }

    const float oscale = (z == 0) ? QSCALE : 1.0f;
#pragma unroll
    for (int ms = 0; ms < 4; ms++) {
        const int mbase = m0 + wm + ms * 16 + lg * 4;
#pragma unroll
        for (int ns = 0; ns < 4; ns++) {
            const int n  = n0 + wn + ns * 16 + lr;
            const float bn = bias[n];
            const int hh = n >> 6, dd = n & 63;
#pragma unroll
            for (int r = 0; r < 4; r++) {
                const float val = (acc[ms][ns][r] + bn) * oscale;
                const int mm = mbase + r;
                const int bb = mm >> 11;
                const int nn = mm & (N_ - 1);
                if (z == 2) {
                    vt[((size_t)(bb * H_ + hh) * D_ + dd) * N_ + nn] = (f16)val;
                } else {
                    f16* dst = (z == 0) ? qh : kh;
                    dst[((size_t)(bb * H_ + hh) * N_ + nn) * D_ + dd] = (f16)val;
                }
            }
        }
    }
}

// ---------------------------------------------------------------------------
// Kernel 3: flash attention — R6-proven per-wave pipeline, repartitioned to
//  2-wave blocks: grid 1024 (32 q-tiles x 32 bh, XCD-swz), 64 q-rows/block,
//  4 blocks/CU. Reg-staged double-buffered K/V with XOR ds_write swizzle.
// ---------------------------------------------------------------------------
__global__ __launch_bounds__(128) void attn_kernel(
    const f16* __restrict__ qh, const f16* __restrict__ kh,
    const f16* __restrict__ vt, f16* __restrict__ ao)
{
    const int bid = blockIdx.x;
    const int swz = (bid & 7) * 128 + (bid >> 3);   // 1024 blocks, 8 XCDs
    const int qt = swz & 31;            // 32 q-tiles of 64 rows
    const int bh = swz >> 5;            // 0..31

    const int tid = threadIdx.x;        // 0..127
    const int w = tid >> 6, lane = tid & 63;
    const int l31 = lane & 31;
    const bool hi = (lane >> 5) != 0;
    const int hib = hi ? 1 : 0;

    const f16* qp = qh + (size_t)bh * N_ * D_;
    const f16* kp = kh + (size_t)bh * N_ * D_;
    const f16* vp = vt + (size_t)bh * D_ * N_;

    const int qrow = qt * 64 + w * 32 + l31;

    f16x8 qf[4];
#pragma unroll
    for (int ks = 0; ks < 4; ks++)
        qf[ks] = *(const f16x8*)&qp[(size_t)qrow * D_ + ks * 16 + hib * 8];

    __shared__ f16 Ks[2][64][64];   // [kv][d], swizzled
    __shared__ f16 Vs[2][64][64];   // [d][kv], swizzled

    // staging: 128 thr; thread covers rows srow+16i (i=0..3), chunk sch
    const int srow = tid >> 3;          // 0..15
    const int sch  = tid & 7;
    const int ssl  = (sch ^ (srow & 7)) * 8;   // (srow+16i)&7 == srow&7

    const f16* kg = kp + (size_t)srow * D_ + sch * 8;
    const f16* vg = vp + (size_t)srow * N_ + sch * 8;

    f32x16 oT0 = {0.f,0.f,0.f,0.f,0.f,0.f,0.f,0.f,0.f,0.f,0.f,0.f,0.f,0.f,0.f,0.f};
    f32x16 oT1 = oT0;
    float mrun = -3.0e38f, lrun = 0.f;

    // prologue: tile 0 into regs
    f16x8 kreg[4], vreg[4];
#pragma unroll
    for (int i = 0; i < 4; i++) {
        kreg[i] = *(const f16x8*)(kg + (size_t)i * 16 * D_);
        vreg[i] = *(const f16x8*)(vg + (size_t)i * 16 * N_);
    }

    constexpr int NT = N_ / 64;         // 32
    int cur = 0;

    for (int t = 0; t < NT; ++t) {
#pragma unroll
        for (int i = 0; i < 4; i++) {
            *(f16x8*)&Ks[cur][srow + 16 * i][ssl] = kreg[i];
            *(f16x8*)&Vs[cur][srow + 16 * i][ssl] = vreg[i];
        }
        if (t + 1 < NT) {
#pragma unroll
            for (int i = 0; i < 4; i++) {
                kreg[i] = *(const f16x8*)(kg + (size_t)(t + 1) * 64 * D_ + (size_t)i * 16 * D_);
                vreg[i] = *(const f16x8*)(vg + (t + 1) * 64 + (size_t)i * 16 * N_);
            }
        }
        __syncthreads();   // buf[cur] writes visible; buf[cur^1] free

        // ---- S^T = K . Q^T ----
        f32x16 sA = {0.f,0.f,0.f,0.f,0.f,0.f,0.f,0.f,0.f,0.f,0.f,0.f,0.f,0.f,0.f,0.f};
        f32x16 sB = sA;
        __builtin_amdgcn_s_setprio(1);
#pragma unroll
        for (int ks = 0; ks < 4; ks++) {
            const int c = (ks * 2 + hib) ^ (l31 & 7);
            const f16x8 kfA = *(const f16x8*)&Ks[cur][l31     ][c * 8];
            const f16x8 kfB = *(const f16x8*)&Ks[cur][l31 + 32][c * 8];
            sA = MFMA32(kfA, qf[ks], sA);
            sB = MFMA32(kfB, qf[ks], sB);
        }
        __builtin_amdgcn_s_setprio(0);

        // ---- tile max (max3-shaped tree) + defer-max ----
        float t16[16];
#pragma unroll
        for (int r = 0; r < 16; r++) t16[r] = fmaxf(sA[r], sB[r]);
        const float u0 = fmaxf(fmaxf(t16[0],  t16[1]),  t16[2]);
        const float u1 = fmaxf(fmaxf(t16[3],  t16[4]),  t16[5]);
        const float u2 = fmaxf(fmaxf(t16[6],  t16[7]),  t16[8]);
        const float u3 = fmaxf(fmaxf(t16[9],  t16[10]), t16[11]);
        const float u4 = fmaxf(fmaxf(t16[12], t16[13]), t16[14]);
        const float v0 = fmaxf(fmaxf(u0, u1), u2);
        const float v1 = fmaxf(fmaxf(u3, u4), t16[15]);
        const float tmax = fmaxf(v0, v1);
        const float pmax = fmaxf(tmax, __shfl_xor(tmax, 32));

        if (!__all(pmax - mrun <= 8.0f)) {
            const float mnew = fmaxf(mrun, pmax);
            const float alpha = __builtin_amdgcn_exp2f(mrun - mnew);
            mrun = mnew;
            lrun *= alpha;
#pragma unroll
            for (int r = 0; r < 16; r++) { oT0[r] *= alpha; oT1[r] *= alpha; }
        }

        float p0 = 0.f, p1 = 0.f, p2 = 0.f, p3 = 0.f;
#pragma unroll
        for (int r = 0; r < 16; r += 4) {
            sA[r]   = __builtin_amdgcn_exp2f(sA[r]   - mrun); p0 += sA[r];
            sA[r+1] = __builtin_amdgcn_exp2f(sA[r+1] - mrun); p1 += sA[r+1];
            sA[r+2] = __builtin_amdgcn_exp2f(sA[r+2] - mrun); p2 += sA[r+2];
            sA[r+3] = __builtin_amdgcn_exp2f(sA[r+3] - mrun); p3 += sA[r+3];
        }
#pragma unroll
        for (int r = 0; r < 16; r += 4) {
            sB[r]   = __builtin_amdgcn_exp2f(sB[r]   - mrun); p0 += sB[r];
            sB[r+1] = __builtin_amdgcn_exp2f(sB[r+1] - mrun); p1 += sB[r+1];
            sB[r+2] = __builtin_amdgcn_exp2f(sB[r+2] - mrun); p2 += sB[r+2];
            sB[r+3] = __builtin_amdgcn_exp2f(sB[r+3] - mrun); p3 += sB[r+3];
        }
        float lsum = (p0 + p1) + (p2 + p3);
        lsum += __shfl_xor(lsum, 32);
        lrun += lsum;

        // ---- P -> B-frag via cvt_pkrtz + shfl_xor(32) + select (PROVEN) ----
        __builtin_amdgcn_s_setprio(1);
#define PVSTEP(PP0,PP1,PP2,PP3,PP4,PP5,PP6,PP7, KSI)                                   \
        {                                                                              \
            const unsigned w0 = __builtin_bit_cast(unsigned, __builtin_amdgcn_cvt_pkrtz(PP0, PP1)); \
            const unsigned w1 = __builtin_bit_cast(unsigned, __builtin_amdgcn_cvt_pkrtz(PP2, PP3)); \
            const unsigned w2 = __builtin_bit_cast(unsigned, __builtin_amdgcn_cvt_pkrtz(PP4, PP5)); \
            const unsigned w3 = __builtin_bit_cast(unsigned, __builtin_amdgcn_cvt_pkrtz(PP6, PP7)); \
            const unsigned x0 = (unsigned)__shfl_xor((int)w0, 32);                     \
            const unsigned x1 = (unsigned)__shfl_xor((int)w1, 32);                     \
            const unsigned x2 = (unsigned)__shfl_xor((int)w2, 32);                     \
            const unsigned x3 = (unsigned)__shfl_xor((int)w3, 32);                     \
            u32x4 pw;                                                                  \
            pw[0] = hi ? x2 : w0;                                                      \
            pw[1] = hi ? x3 : w1;                                                      \
            pw[2] = hi ? w2 : x0;                                                      \
            pw[3] = hi ? w3 : x1;                                                      \
            const f16x8 pa = __builtin_bit_cast(f16x8, pw);                            \
            const int c = ((KSI) * 2 + hib) ^ (l31 & 7);                               \
            const f16x8 vf0 = *(const f16x8*)&Vs[cur][l31     ][c * 8];                \
            const f16x8 vf1 = *(const f16x8*)&Vs[cur][l31 + 32][c * 8];                \
            oT0 = MFMA32(vf0, pa, oT0);                                                \
            oT1 = MFMA32(vf1, pa, oT1);                                                \
        }
        PVSTEP(sA[0],sA[1],sA[2],sA[3],sA[4],sA[5],sA[6],sA[7], 0)
        PVSTEP(sA[8],sA[9],sA[10],sA[11],sA[12],sA[13],sA[14],sA[15], 1)
        PVSTEP(sB[0],sB[1],sB[2],sB[3],sB[4],sB[5],sB[6],sB[7], 2)
        PVSTEP(sB[8],sB[9],sB[10],sB[11],sB[12],sB[13],sB[14],sB[15], 3)
#undef PVSTEP
        __builtin_amdgcn_s_setprio(0);

        cur ^= 1;
    }

    // ---- epilogue: O[q][d] = O^T / lrun ----
    const float inv = 1.0f / lrun;
    const int b = bh >> 4, h = bh & 15;
    f16* dst = ao + (size_t)(b * N_ + qrow) * E_ + h * 64 + hib * 4;
#pragma unroll
    for (int g = 0; g < 4; g++) {
        f16x4 o0, o1;
#pragma unroll
        for (int j = 0; j < 4; j++) {
            o0[j] = (f16)(oT0[g * 4 + j] * inv);
            o1[j] = (f16)(oT1[g * 4 + j] * inv);
        }
        *(f16x4*)&dst[8 * g]      = o0;
        *(f16x4*)&dst[8 * g + 32] = o1;
    }
}

// ---------------------------------------------------------------------------
// Kernel 4: output GEMM, m97-structure.  out[m,n] = ao[m,:].Wo[n,:] + bo[n]
// ---------------------------------------------------------------------------
__global__ __launch_bounds__(256) void out_gemm(
    const f16* __restrict__ ao, const f16* __restrict__ Wo,
    const float* __restrict__ bo, float* __restrict__ out)
{
    __shared__ f16 As[128][32];
    __shared__ f16 Bs[128][32];

    const int bid = blockIdx.x;
    const int lin = (bid & 7) * 32 + (bid >> 3);
    const int m0  = (lin >> 3) * 128;
    const int n0  = (lin & 7) * 128;

    const int tid  = threadIdx.x;
    const int lane = tid & 63, w = tid >> 6;
    const int lr = lane & 15, lg = lane >> 4;
    const int wm = (w >> 1) * 64, wn = (w & 1) * 64;

    const int gch = ((lane & 3) ^ ((lane >> 3) & 3)) * 8;
    const f16* ag = ao + (size_t)(m0 + w * 32 + (lane >> 2)) * E_ + gch;
    const f16* bg = Wo + (size_t)(n0 + w * 32 + (lane >> 2)) * E_ + gch;
    f16* al0 = &As[w * 32][0];
    f16* al1 = &As[w * 32 + 16][0];
    f16* bl0 = &Bs[w * 32][0];
    f16* bl1 = &Bs[w * 32 + 16][0];

    const int ca = (lg ^ ((lr >> 1) & 3)) * 8;

    f32x4 acc[4][4];
#pragma unroll
    for (int i = 0; i < 4; i++)
#pragma unroll
        for (int j = 0; j < 4; j++) acc[i][j] = (f32x4){0.f, 0.f, 0.f, 0.f};

    for (int t = 0; t < E_ / 32; ++t) {
        __syncthreads();
        gload_lds16(ag,            al0);
        gload_lds16(ag + 16 * E_,  al1);
        gload_lds16(bg,            bl0);
        gload_lds16(bg + 16 * E_,  bl1);
        ag += 32; bg += 32;
        __syncthreads();

        f16x8 af[4], bfr[4];
#pragma unroll
        for (int ms = 0; ms < 4; ms++) af[ms]  = *(const f16x8*)&As[wm + ms * 16 + lr][ca];
#pragma unroll
        for (int ns = 0; ns < 4; ns++) bfr[ns] = *(const f16x8*)&Bs[wn + ns * 16 + lr][ca];
        __builtin_amdgcn_s_setprio(1);
#pragma unroll
        for (int ms = 0; ms < 4; ms++)
#pragma unroll
            for (int ns = 0; ns < 4; ns++)
                acc[ms][ns] = MFMA16(af[ms], bfr[ns], acc[ms][ns]);
        __builtin_amdgcn_s_setprio(0);
    }

#pragma unroll
    for (int ms = 0; ms < 4; ms++) {
        const int mbase = m0 + wm + ms * 16 + lg * 4;
#pragma unroll
        for (int ns = 0; ns < 4; ns++) {
            const int n = n0 + wn + ns * 16 + lr;
            const float bn = bo[n];
#pragma unroll
            for (int r = 0; r < 4; r++) {
                out[(size_t)(mbase + r) * E_ + n] = acc[ms][ns][r] + bn;
            }
        }
    }
}

// ---------------------------------------------------------------------------
extern "C" void kernel_launch(void* const* d_in, const int* in_sizes, int n_in,
                              void* d_out, int out_size, void* d_ws, size_t ws_size,
                              hipStream_t stream) {
    const float* q  = (const float*)d_in[0];
    const float* k  = (const float*)d_in[1];
    const float* v  = (const float*)d_in[2];
    const float* Wq = (const float*)d_in[3];
    const float* bq = (const float*)d_in[4];
    const float* Wk = (const float*)d_in[5];
    const float* bk = (const float*)d_in[6];
    const float* Wv = (const float*)d_in[7];
    const float* bv = (const float*)d_in[8];
    const float* Wo = (const float*)d_in[9];
    const float* bo = (const float*)d_in[10];
    float* out = (float*)d_out;

    char* ws = (char*)d_ws;
    f16* cast = (f16*)ws;
    f16* Wb   = cast;
    f16* Aall = cast + (size_t)4 * E_ * E_;
    f16* qh = (f16*)(ws + (size_t)32 * 1024 * 1024);
    f16* kh = (f16*)(ws + (size_t)40 * 1024 * 1024);
    f16* vt = (f16*)(ws + (size_t)48 * 1024 * 1024);
    f16* ao = (f16*)(ws + (size_t)56 * 1024 * 1024);

    cast_all<<<16384, 256, 0, stream>>>(Wq, Wk, Wv, Wo, q, k, v, cast);
    proj_gemm<<<768, 256, 0, stream>>>(Aall, Wb, bq, bk, bv, qh, kh, vt);
    attn_kernel<<<1024, 128, 0, stream>>>(qh, kh, vt, ao);
    out_gemm<<<256, 256, 0, stream>>>(ao, Wb + (size_t)3 * E_ * E_, bo, out);
}

// Round 12
// 149.081 us; speedup vs baseline: 1.3078x; 1.0484x over previous
//
#include <hip/hip_runtime.h>

typedef _Float16 f16;
typedef __attribute__((ext_vector_type(2))) _Float16 f16x2;
typedef __attribute__((ext_vector_type(4))) _Float16 f16x4;
typedef __attribute__((ext_vector_type(8))) _Float16 f16x8;
typedef __attribute__((ext_vector_type(4))) float    f32x4;
typedef __attribute__((ext_vector_type(16))) float   f32x16;
typedef __attribute__((ext_vector_type(4))) unsigned u32x4;

static constexpr int B_ = 2, N_ = 2048, E_ = 1024, H_ = 16, D_ = 64;
static constexpr int M_ = B_ * N_;   // 4096

#define MFMA16(a, b, c) __builtin_amdgcn_mfma_f32_16x16x32_f16(a, b, c, 0, 0, 0)
#define MFMA32(a, b, c) __builtin_amdgcn_mfma_f32_32x32x16_f16(a, b, c, 0, 0, 0)

// q-projection scale: 1/sqrt(D) * log2(e)  (softmax done in exp2 domain)
#define QSCALE 0.18033688011112042f

// async global(16B/lane) -> LDS (wave-uniform base + lane*16)
__device__ __forceinline__ void gload_lds16(const f16* g, f16* l) {
    typedef __attribute__((address_space(1))) const unsigned gu32;
    typedef __attribute__((address_space(3))) unsigned       lu32;
    __builtin_amdgcn_global_load_lds((gu32*)g, (lu32*)l, 16, 0, 0);
}

// ---------------------------------------------------------------------------
// Kernel 1: cast weights (4*E*E) AND q/k/v (3*M*E) fp32 -> f16 into one flat
// region: [Wq|Wk|Wv|Wo | q|k|v].
// ---------------------------------------------------------------------------
__global__ __launch_bounds__(256) void cast_all(
    const float* __restrict__ Wq, const float* __restrict__ Wk,
    const float* __restrict__ Wv, const float* __restrict__ Wo,
    const float* __restrict__ q, const float* __restrict__ k,
    const float* __restrict__ v, f16* __restrict__ dst)
{
    const int i = (blockIdx.x * 256 + threadIdx.x) * 4;
    const float* s;
    int j;
    if (i < 4 * E_ * E_) {
        const int which = i >> 20;                        // E*E = 2^20
        s = (which == 0) ? Wq : (which == 1) ? Wk : (which == 2) ? Wv : Wo;
        j = i & (E_ * E_ - 1);
    } else {
        const int t = i - 4 * E_ * E_;
        const int which = t >> 22;                        // M*E = 2^22
        s = (which == 0) ? q : (which == 1) ? k : v;
        j = t & (M_ * E_ - 1);
    }
    const f32x4 f = *(const f32x4*)&s[j];
    f16x4 o;
    o[0] = (f16)f[0]; o[1] = (f16)f[1]; o[2] = (f16)f[2]; o[3] = (f16)f[3];
    *(f16x4*)&dst[i] = o;
}

// ---------------------------------------------------------------------------
// Kernel 2: projection GEMM, m97-structure (global_load_lds, linear LDS,
//   XOR-chunk swizzle via pre-swizzled global source).  R6-proven version.
// ---------------------------------------------------------------------------
__global__ __launch_bounds__(256) void proj_gemm(
    const f16* __restrict__ Aall, const f16* __restrict__ Wb,
    const float* __restrict__ bq, const float* __restrict__ bk, const float* __restrict__ bv,
    f16* __restrict__ qh, f16* __restrict__ kh, f16* __restrict__ vt)
{
    const int bid  = blockIdx.x;
    const int lin  = (bid & 7) * 96 + (bid >> 3);
    const int z    = lin >> 8;
    const int rem  = lin & 255;
    const int m0   = (rem >> 3) * 128;
    const int n0   = (rem & 7) * 128;

    const f16* A    = Aall + (size_t)z * M_ * E_;
    const f16* W    = Wb + (size_t)z * E_ * E_;
    const float* bias = (z == 0) ? bq : (z == 1) ? bk : bv;

    __shared__ f16 As[128][32];
    __shared__ f16 Bs[128][32];

    const int tid  = threadIdx.x;
    const int lane = tid & 63, w = tid >> 6;
    const int lr = lane & 15, lg = lane >> 4;
    const int wm = (w >> 1) * 64, wn = (w & 1) * 64;

    const int gch = ((lane & 3) ^ ((lane >> 3) & 3)) * 8;
    const f16* ag = A + (size_t)(m0 + w * 32 + (lane >> 2)) * E_ + gch;
    const f16* bg = W + (size_t)(n0 + w * 32 + (lane >> 2)) * E_ + gch;
    f16* al0 = &As[w * 32][0];
    f16* al1 = &As[w * 32 + 16][0];
    f16* bl0 = &Bs[w * 32][0];
    f16* bl1 = &Bs[w * 32 + 16][0];

    const int ca = (lg ^ ((lr >> 1) & 3)) * 8;

    f32x4 acc[4][4];
#pragma unroll
    for (int i = 0; i < 4; i++)
#pragma unroll
        for (int j = 0; j < 4; j++) acc[i][j] = (f32x4){0.f, 0.f, 0.f, 0.f};

    for (int t = 0; t < E_ / 32; ++t) {
        __syncthreads();
        gload_lds16(ag,            al0);
        gload_lds16(ag + 16 * E_,  al1);
        gload_lds16(bg,            bl0);
        gload_lds16(bg + 16 * E_,  bl1);
        ag += 32; bg += 32;
        __syncthreads();

        f16x8 af[4], bfr[4];
#pragma unroll
        for (int ms = 0; ms < 4; ms++) af[ms]  = *(const f16x8*)&As[wm + ms * 16 + lr][ca];
#pragma unroll
        for (int ns = 0; ns < 4; ns++) bfr[ns] = *(const f16x8*)&Bs[wn + ns * 16 + lr][ca];
        __builtin_amdgcn_s_setprio(1);
#pragma unroll
        for (int ms = 0; ms < 4; ms++)
#pragma unroll
            for (int ns = 0; ns < 4; ns++)
                acc[ms][ns] = MFMA16(af[ms], bfr[ns], acc[ms][ns]);
        __builtin_amdgcn_s_setprio(0);
    }

    const float oscale = (z == 0) ? QSCALE : 1.0f;
#pragma unroll
    for (int ms = 0; ms < 4; ms++) {
        const int mbase = m0 + wm + ms * 16 + lg * 4;
#pragma unroll
        for (int ns = 0; ns < 4; ns++) {
            const int n  = n0 + wn + ns * 16 + lr;
            const float bn = bias[n];
            const int hh = n >> 6, dd = n & 63;
#pragma unroll
            for (int r = 0; r < 4; r++) {
                const float val = (acc[ms][ns][r] + bn) * oscale;
                const int mm = mbase + r;
                const int bb = mm >> 11;
                const int nn = mm & (N_ - 1);
                if (z == 2) {
                    vt[((size_t)(bb * H_ + hh) * D_ + dd) * N_ + nn] = (f16)val;
                } else {
                    f16* dst = (z == 0) ? qh : kh;
                    dst[((size_t)(bb * H_ + hh) * N_ + nn) * D_ + dd] = (f16)val;
                }
            }
        }
    }
}

// ---------------------------------------------------------------------------
// Kernel 3: flash attention — R6-proven per-subtile math (shfl_xor cross-half,
//  XOR ds_write swizzle, defer-max), restructured to KVBLK=128: two 64-kv
//  subtiles per staged round, QK of both issued before softmax of either so
//  the scheduler can overlap subtile-B MFMAs with subtile-A softmax VALU.
//  Grid 512 (16 q-tiles x 32 bh, XCD-swz), 4 waves, 128 q-rows/block.
// ---------------------------------------------------------------------------
__global__ __launch_bounds__(256) void attn_kernel(
    const f16* __restrict__ qh, const f16* __restrict__ kh,
    const f16* __restrict__ vt, f16* __restrict__ ao)
{
    const int bid = blockIdx.x;
    const int swz = (bid & 7) * 64 + (bid >> 3);   // 512 blocks, 8 XCDs
    const int qt = swz & 15;            // 16 q-tiles of 128 rows
    const int bh = swz >> 4;            // 0..31

    const int tid = threadIdx.x;
    const int w = tid >> 6, lane = tid & 63;
    const int l31 = lane & 31;
    const bool hi = (lane >> 5) != 0;
    const int hib = hi ? 1 : 0;

    const f16* qp = qh + (size_t)bh * N_ * D_;
    const f16* kp = kh + (size_t)bh * N_ * D_;
    const f16* vp = vt + (size_t)bh * D_ * N_;

    const int qrow = qt * 128 + w * 32 + l31;

    f16x8 qf[4];
#pragma unroll
    for (int ks = 0; ks < 4; ks++)
        qf[ks] = *(const f16x8*)&qp[(size_t)qrow * D_ + ks * 16 + hib * 8];

    __shared__ f16 Ks[2][2][64][64];   // [buf][sub][kv][d], swizzled
    __shared__ f16 Vs[2][2][64][64];   // [buf][sub][d][kv], swizzled

    const int srow = tid >> 3;          // 0..31
    const int sch  = tid & 7;
    const int ssl  = (sch ^ (srow & 7)) * 8;

    const f16* kg0 = kp + (size_t)srow * D_ + sch * 8;
    const f16* kg1 = kg0 + (size_t)32 * D_;
    const f16* vg0 = vp + (size_t)srow * N_ + sch * 8;
    const f16* vg1 = vg0 + (size_t)32 * N_;

    f32x16 oT0 = {0.f,0.f,0.f,0.f,0.f,0.f,0.f,0.f,0.f,0.f,0.f,0.f,0.f,0.f,0.f,0.f};
    f32x16 oT1 = oT0;
    float mrun = -3.0e38f, lrun = 0.f;

    // prologue: round 0 (kv 0..127) into regs
    f16x8 krA0 = *(const f16x8*)(kg0);
    f16x8 krA1 = *(const f16x8*)(kg1);
    f16x8 krB0 = *(const f16x8*)(kg0 + (size_t)64 * D_);
    f16x8 krB1 = *(const f16x8*)(kg1 + (size_t)64 * D_);
    f16x8 vrA0 = *(const f16x8*)(vg0);
    f16x8 vrA1 = *(const f16x8*)(vg1);
    f16x8 vrB0 = *(const f16x8*)(vg0 + 64);
    f16x8 vrB1 = *(const f16x8*)(vg1 + 64);

    // proven softmax + PV block (R6), parameterized by S-regs and V-tile
#define PVSTEP(VT, PP0,PP1,PP2,PP3,PP4,PP5,PP6,PP7, KSI)                               \
        {                                                                              \
            const unsigned w0 = __builtin_bit_cast(unsigned, __builtin_amdgcn_cvt_pkrtz(PP0, PP1)); \
            const unsigned w1 = __builtin_bit_cast(unsigned, __builtin_amdgcn_cvt_pkrtz(PP2, PP3)); \
            const unsigned w2 = __builtin_bit_cast(unsigned, __builtin_amdgcn_cvt_pkrtz(PP4, PP5)); \
            const unsigned w3 = __builtin_bit_cast(unsigned, __builtin_amdgcn_cvt_pkrtz(PP6, PP7)); \
            const unsigned x0 = (unsigned)__shfl_xor((int)w0, 32);                     \
            const unsigned x1 = (unsigned)__shfl_xor((int)w1, 32);                     \
            const unsigned x2 = (unsigned)__shfl_xor((int)w2, 32);                     \
            const unsigned x3 = (unsigned)__shfl_xor((int)w3, 32);                     \
            u32x4 pw;                                                                  \
            pw[0] = hi ? x2 : w0;                                                      \
            pw[1] = hi ? x3 : w1;                                                      \
            pw[2] = hi ? w2 : x0;                                                      \
            pw[3] = hi ? w3 : x1;                                                      \
            const f16x8 pa = __builtin_bit_cast(f16x8, pw);                            \
            const int c = ((KSI) * 2 + hib) ^ (l31 & 7);                               \
            const f16x8 vf0 = *(const f16x8*)&VT[l31     ][c * 8];                     \
            const f16x8 vf1 = *(const f16x8*)&VT[l31 + 32][c * 8];                     \
            oT0 = MFMA32(vf0, pa, oT0);                                                \
            oT1 = MFMA32(vf1, pa, oT1);                                                \
        }

#define SOFTMAX_PV(SA, SB, VT)                                                         \
    {                                                                                  \
        float t16[16];                                                                 \
        _Pragma("unroll")                                                              \
        for (int r = 0; r < 16; r++) t16[r] = fmaxf(SA[r], SB[r]);                     \
        _Pragma("unroll")                                                              \
        for (int d = 8; d >= 1; d >>= 1)                                               \
            for (int r = 0; r < d; r++) t16[r] = fmaxf(t16[r], t16[r + d]);            \
        const float pmax = fmaxf(t16[0], __shfl_xor(t16[0], 32));                      \
        if (!__all(pmax - mrun <= 8.0f)) {                                             \
            const float mnew = fmaxf(mrun, pmax);                                      \
            const float alpha = __builtin_amdgcn_exp2f(mrun - mnew);                   \
            mrun = mnew;                                                               \
            lrun *= alpha;                                                             \
            _Pragma("unroll")                                                          \
            for (int r = 0; r < 16; r++) { oT0[r] *= alpha; oT1[r] *= alpha; }         \
        }                                                                              \
        float p0 = 0.f, p1 = 0.f, p2 = 0.f, p3 = 0.f;                                  \
        _Pragma("unroll")                                                              \
        for (int r = 0; r < 16; r += 4) {                                              \
            SA[r]   = __builtin_amdgcn_exp2f(SA[r]   - mrun); p0 += SA[r];             \
            SA[r+1] = __builtin_amdgcn_exp2f(SA[r+1] - mrun); p1 += SA[r+1];           \
            SA[r+2] = __builtin_amdgcn_exp2f(SA[r+2] - mrun); p2 += SA[r+2];           \
            SA[r+3] = __builtin_amdgcn_exp2f(SA[r+3] - mrun); p3 += SA[r+3];           \
        }                                                                              \
        _Pragma("unroll")                                                              \
        for (int r = 0; r < 16; r += 4) {                                              \
            SB[r]   = __builtin_amdgcn_exp2f(SB[r]   - mrun); p0 += SB[r];             \
            SB[r+1] = __builtin_amdgcn_exp2f(SB[r+1] - mrun); p1 += SB[r+1];           \
            SB[r+2] = __builtin_amdgcn_exp2f(SB[r+2] - mrun); p2 += SB[r+2];           \
            SB[r+3] = __builtin_amdgcn_exp2f(SB[r+3] - mrun); p3 += SB[r+3];           \
        }                                                                              \
        float lsum = (p0 + p1) + (p2 + p3);                                            \
        lsum += __shfl_xor(lsum, 32);                                                  \
        lrun += lsum;                                                                  \
        __builtin_amdgcn_s_setprio(1);                                                 \
        PVSTEP(VT, SA[0],SA[1],SA[2],SA[3],SA[4],SA[5],SA[6],SA[7], 0)                 \
        PVSTEP(VT, SA[8],SA[9],SA[10],SA[11],SA[12],SA[13],SA[14],SA[15], 1)           \
        PVSTEP(VT, SB[0],SB[1],SB[2],SB[3],SB[4],SB[5],SB[6],SB[7], 2)                 \
        PVSTEP(VT, SB[8],SB[9],SB[10],SB[11],SB[12],SB[13],SB[14],SB[15], 3)           \
        __builtin_amdgcn_s_setprio(0);                                                 \
    }

    constexpr int NR = N_ / 128;        // 16 rounds
    int cur = 0;

    for (int t = 0; t < NR; ++t) {
        *(f16x8*)&Ks[cur][0][srow     ][ssl] = krA0;
        *(f16x8*)&Ks[cur][0][srow + 32][ssl] = krA1;
        *(f16x8*)&Ks[cur][1][srow     ][ssl] = krB0;
        *(f16x8*)&Ks[cur][1][srow + 32][ssl] = krB1;
        *(f16x8*)&Vs[cur][0][srow     ][ssl] = vrA0;
        *(f16x8*)&Vs[cur][0][srow + 32][ssl] = vrA1;
        *(f16x8*)&Vs[cur][1][srow     ][ssl] = vrB0;
        *(f16x8*)&Vs[cur][1][srow + 32][ssl] = vrB1;
        if (t + 1 < NR) {
            const size_t ko = (size_t)(t + 1) * 128;
            krA0 = *(const f16x8*)(kg0 + ko * D_);
            krA1 = *(const f16x8*)(kg1 + ko * D_);
            krB0 = *(const f16x8*)(kg0 + (ko + 64) * D_);
            krB1 = *(const f16x8*)(kg1 + (ko + 64) * D_);
            vrA0 = *(const f16x8*)(vg0 + ko);
            vrA1 = *(const f16x8*)(vg1 + ko);
            vrB0 = *(const f16x8*)(vg0 + ko + 64);
            vrB1 = *(const f16x8*)(vg1 + ko + 64);
        }
        __syncthreads();

        // ---- QK^T for BOTH subtiles (independent MFMA clusters) ----
        f32x16 sA0 = {0.f,0.f,0.f,0.f,0.f,0.f,0.f,0.f,0.f,0.f,0.f,0.f,0.f,0.f,0.f,0.f};
        f32x16 sB0 = sA0, sA1 = sA0, sB1 = sA0;
        __builtin_amdgcn_s_setprio(1);
#pragma unroll
        for (int ks = 0; ks < 4; ks++) {
            const int c = (ks * 2 + hib) ^ (l31 & 7);
            const f16x8 kfA = *(const f16x8*)&Ks[cur][0][l31     ][c * 8];
            const f16x8 kfB = *(const f16x8*)&Ks[cur][0][l31 + 32][c * 8];
            sA0 = MFMA32(kfA, qf[ks], sA0);
            sB0 = MFMA32(kfB, qf[ks], sB0);
        }
#pragma unroll
        for (int ks = 0; ks < 4; ks++) {
            const int c = (ks * 2 + hib) ^ (l31 & 7);
            const f16x8 kfA = *(const f16x8*)&Ks[cur][1][l31     ][c * 8];
            const f16x8 kfB = *(const f16x8*)&Ks[cur][1][l31 + 32][c * 8];
            sA1 = MFMA32(kfA, qf[ks], sA1);
            sB1 = MFMA32(kfB, qf[ks], sB1);
        }
        __builtin_amdgcn_s_setprio(0);

        // ---- softmax+PV subtile A, then B (B's QK already done -> overlap) ----
        SOFTMAX_PV(sA0, sB0, Vs[cur][0]);
        SOFTMAX_PV(sA1, sB1, Vs[cur][1]);

        cur ^= 1;
    }
#undef SOFTMAX_PV
#undef PVSTEP

    // ---- epilogue: O[q][d] = O^T / lrun ----
    const float inv = 1.0f / lrun;
    const int b = bh >> 4, h = bh & 15;
    f16* dst = ao + (size_t)(b * N_ + qrow) * E_ + h * 64 + hib * 4;
#pragma unroll
    for (int g = 0; g < 4; g++) {
        f16x4 o0, o1;
#pragma unroll
        for (int j = 0; j < 4; j++) {
            o0[j] = (f16)(oT0[g * 4 + j] * inv);
            o1[j] = (f16)(oT1[g * 4 + j] * inv);
        }
        *(f16x4*)&dst[8 * g]      = o0;
        *(f16x4*)&dst[8 * g + 32] = o1;
    }
}

// ---------------------------------------------------------------------------
// Kernel 4: output GEMM, m97-structure.  out[m,n] = ao[m,:].Wo[n,:] + bo[n]
// ---------------------------------------------------------------------------
__global__ __launch_bounds__(256) void out_gemm(
    const f16* __restrict__ ao, const f16* __restrict__ Wo,
    const float* __restrict__ bo, float* __restrict__ out)
{
    __shared__ f16 As[128][32];
    __shared__ f16 Bs[128][32];

    const int bid = blockIdx.x;
    const int lin = (bid & 7) * 32 + (bid >> 3);
    const int m0  = (lin >> 3) * 128;
    const int n0  = (lin & 7) * 128;

    const int tid  = threadIdx.x;
    const int lane = tid & 63, w = tid >> 6;
    const int lr = lane & 15, lg = lane >> 4;
    const int wm = (w >> 1) * 64, wn = (w & 1) * 64;

    const int gch = ((lane & 3) ^ ((lane >> 3) & 3)) * 8;
    const f16* ag = ao + (size_t)(m0 + w * 32 + (lane >> 2)) * E_ + gch;
    const f16* bg = Wo + (size_t)(n0 + w * 32 + (lane >> 2)) * E_ + gch;
    f16* al0 = &As[w * 32][0];
    f16* al1 = &As[w * 32 + 16][0];
    f16* bl0 = &Bs[w * 32][0];
    f16* bl1 = &Bs[w * 32 + 16][0];

    const int ca = (lg ^ ((lr >> 1) & 3)) * 8;

    f32x4 acc[4][4];
#pragma unroll
    for (int i = 0; i < 4; i++)
#pragma unroll
        for (int j = 0; j < 4; j++) acc[i][j] = (f32x4){0.f, 0.f, 0.f, 0.f};

    for (int t = 0; t < E_ / 32; ++t) {
        __syncthreads();
        gload_lds16(ag,            al0);
        gload_lds16(ag + 16 * E_,  al1);
        gload_lds16(bg,            bl0);
        gload_lds16(bg + 16 * E_,  bl1);
        ag += 32; bg += 32;
        __syncthreads();

        f16x8 af[4], bfr[4];
#pragma unroll
        for (int ms = 0; ms < 4; ms++) af[ms]  = *(const f16x8*)&As[wm + ms * 16 + lr][ca];
#pragma unroll
        for (int ns = 0; ns < 4; ns++) bfr[ns] = *(const f16x8*)&Bs[wn + ns * 16 + lr][ca];
        __builtin_amdgcn_s_setprio(1);
#pragma unroll
        for (int ms = 0; ms < 4; ms++)
#pragma unroll
            for (int ns = 0; ns < 4; ns++)
                acc[ms][ns] = MFMA16(af[ms], bfr[ns], acc[ms][ns]);
        __builtin_amdgcn_s_setprio(0);
    }

#pragma unroll
    for (int ms = 0; ms < 4; ms++) {
        const int mbase = m0 + wm + ms * 16 + lg * 4;
#pragma unroll
        for (int ns = 0; ns < 4; ns++) {
            const int n = n0 + wn + ns * 16 + lr;
            const float bn = bo[n];
#pragma unroll
            for (int r = 0; r < 4; r++) {
                out[(size_t)(mbase + r) * E_ + n] = acc[ms][ns][r] + bn;
            }
        }
    }
}

// ---------------------------------------------------------------------------
extern "C" void kernel_launch(void* const* d_in, const int* in_sizes, int n_in,
                              void* d_out, int out_size, void* d_ws, size_t ws_size,
                              hipStream_t stream) {
    const float* q  = (const float*)d_in[0];
    const float* k  = (const float*)d_in[1];
    const float* v  = (const float*)d_in[2];
    const float* Wq = (const float*)d_in[3];
    const float* bq = (const float*)d_in[4];
    const float* Wk = (const float*)d_in[5];
    const float* bk = (const float*)d_in[6];
    const float* Wv = (const float*)d_in[7];
    const float* bv = (const float*)d_in[8];
    const float* Wo = (const float*)d_in[9];
    const float* bo = (const float*)d_in[10];
    float* out = (float*)d_out;

    char* ws = (char*)d_ws;
    f16* cast = (f16*)ws;
    f16* Wb   = cast;
    f16* Aall = cast + (size_t)4 * E_ * E_;
    f16* qh = (f16*)(ws + (size_t)32 * 1024 * 1024);
    f16* kh = (f16*)(ws + (size_t)40 * 1024 * 1024);
    f16* vt = (f16*)(ws + (size_t)48 * 1024 * 1024);
    f16* ao = (f16*)(ws + (size_t)56 * 1024 * 1024);

    cast_all<<<16384, 256, 0, stream>>>(Wq, Wk, Wv, Wo, q, k, v, cast);
    proj_gemm<<<768, 256, 0, stream>>>(Aall, Wb, bq, bk, bv, qh, kh, vt);
    attn_kernel<<<512, 256, 0, stream>>>(qh, kh, vt, ao);
    out_gemm<<<256, 256, 0, stream>>>(ao, Wb + (size_t)3 * E_ * E_, bo, out);
}